// Round 6
// baseline (1619.125 us; speedup 1.0000x reference)
//
#include <hip/hip_runtime.h>
#include <cstdint>

#define H_DIM 1024
#define S_LEN 256
#define NBLK_SCAN 64
#define NWAVE 16
#define GDEPTH 16
#define DOMC ((float)(1.0 - 0.9))
#define EPS_LN 1e-5f

typedef float v2f __attribute__((ext_vector_type(2)));

// ---------------------------------------------------------------------------
// DPP 64-lane all-reduce sum.
// ---------------------------------------------------------------------------
template <int CTRL, int RMASK, bool BC>
__device__ __forceinline__ float dpp_term(float x) {
    return __int_as_float(__builtin_amdgcn_update_dpp(
        0, __float_as_int(x), CTRL, RMASK, 0xf, BC));
}
__device__ __forceinline__ float wave_reduce_sum(float x) {
    x += dpp_term<0x111, 0xf, true>(x);
    x += dpp_term<0x112, 0xf, true>(x);
    x += dpp_term<0x114, 0xf, true>(x);
    x += dpp_term<0x118, 0xf, true>(x);
    x += dpp_term<0x142, 0xa, false>(x);
    x += dpp_term<0x143, 0xc, false>(x);
    return __int_as_float(__builtin_amdgcn_readlane(__float_as_int(x), 63));
}

// LDS-only release: order ring-data ds_writes before the flag ds_write.
__device__ __forceinline__ void lds_release_fence() {
    asm volatile("s_waitcnt lgkmcnt(0)" ::: "memory");
}

// ---------------------------------------------------------------------------
// MALL-coherent (sc0 sc1) global ops.
// ---------------------------------------------------------------------------
__device__ __forceinline__ int llc_load_int(const int* p) {
    int v;
    asm volatile("global_load_dword %0, %1, off sc0 sc1\n\ts_waitcnt vmcnt(0)"
                 : "=v"(v) : "v"(p) : "memory");
    return v;
}
__device__ __forceinline__ void llc_store_int(int* p, int v) {
    asm volatile("global_store_dword %0, %1, off sc0 sc1" :: "v"(p), "v"(v)
                 : "memory");
}
__device__ __forceinline__ void llc_store_row_nowait(float* base, const float* h) {
    asm volatile(
        "global_store_dword %16, %0, off sc0 sc1\n\t"
        "global_store_dword %16, %1, off offset:256 sc0 sc1\n\t"
        "global_store_dword %16, %2, off offset:512 sc0 sc1\n\t"
        "global_store_dword %16, %3, off offset:768 sc0 sc1\n\t"
        "global_store_dword %16, %4, off offset:1024 sc0 sc1\n\t"
        "global_store_dword %16, %5, off offset:1280 sc0 sc1\n\t"
        "global_store_dword %16, %6, off offset:1536 sc0 sc1\n\t"
        "global_store_dword %16, %7, off offset:1792 sc0 sc1\n\t"
        "global_store_dword %16, %8, off offset:2048 sc0 sc1\n\t"
        "global_store_dword %16, %9, off offset:2304 sc0 sc1\n\t"
        "global_store_dword %16, %10, off offset:2560 sc0 sc1\n\t"
        "global_store_dword %16, %11, off offset:2816 sc0 sc1\n\t"
        "global_store_dword %16, %12, off offset:3072 sc0 sc1\n\t"
        "global_store_dword %16, %13, off offset:3328 sc0 sc1\n\t"
        "global_store_dword %16, %14, off offset:3584 sc0 sc1\n\t"
        "global_store_dword %16, %15, off offset:3840 sc0 sc1"
        :: "v"(h[0]), "v"(h[1]), "v"(h[2]), "v"(h[3]),
           "v"(h[4]), "v"(h[5]), "v"(h[6]), "v"(h[7]),
           "v"(h[8]), "v"(h[9]), "v"(h[10]), "v"(h[11]),
           "v"(h[12]), "v"(h[13]), "v"(h[14]), "v"(h[15]), "v"(base)
        : "memory");
}
// Flag-lag-1 publish: issue beat-L data first, then vmcnt(16) (drains beat L-1's
// 16 stores + the old flag: 17 vmem ops/step, in-order retirement), then release
// flag L-1. No stall: the waited ops were issued a full step earlier.
__device__ __forceinline__ void llc_publish_lag1(float* dbase, int* flagp,
                                                 int flagval, const float* h) {
    asm volatile(
        "global_store_dword %16, %0, off sc0 sc1\n\t"
        "global_store_dword %16, %1, off offset:256 sc0 sc1\n\t"
        "global_store_dword %16, %2, off offset:512 sc0 sc1\n\t"
        "global_store_dword %16, %3, off offset:768 sc0 sc1\n\t"
        "global_store_dword %16, %4, off offset:1024 sc0 sc1\n\t"
        "global_store_dword %16, %5, off offset:1280 sc0 sc1\n\t"
        "global_store_dword %16, %6, off offset:1536 sc0 sc1\n\t"
        "global_store_dword %16, %7, off offset:1792 sc0 sc1\n\t"
        "global_store_dword %16, %8, off offset:2048 sc0 sc1\n\t"
        "global_store_dword %16, %9, off offset:2304 sc0 sc1\n\t"
        "global_store_dword %16, %10, off offset:2560 sc0 sc1\n\t"
        "global_store_dword %16, %11, off offset:2816 sc0 sc1\n\t"
        "global_store_dword %16, %12, off offset:3072 sc0 sc1\n\t"
        "global_store_dword %16, %13, off offset:3328 sc0 sc1\n\t"
        "global_store_dword %16, %14, off offset:3584 sc0 sc1\n\t"
        "global_store_dword %16, %15, off offset:3840 sc0 sc1\n\t"
        "s_waitcnt vmcnt(16)\n\t"
        "global_store_dword %17, %18, off sc0 sc1"
        :: "v"(h[0]), "v"(h[1]), "v"(h[2]), "v"(h[3]),
           "v"(h[4]), "v"(h[5]), "v"(h[6]), "v"(h[7]),
           "v"(h[8]), "v"(h[9]), "v"(h[10]), "v"(h[11]),
           "v"(h[12]), "v"(h[13]), "v"(h[14]), "v"(h[15]),
           "v"(dbase), "v"(flagp), "v"(flagval)
        : "memory");
}
__device__ __forceinline__ void llc_release(int* flagp, int flagval) {
    asm volatile("s_waitcnt vmcnt(0)\n\t"
                 "global_store_dword %0, %1, off sc0 sc1"
                 :: "v"(flagp), "v"(flagval) : "memory");
}

// Async DMA of one 4 KB ring slot (global -> LDS staging), MALL-coherent.
// aux 0x11 = SC0|SC1 (gfx940+ CPol encoding). vmcnt-tracked.
__device__ __forceinline__ void dma_slot(const float* gslot, float* stg, int l) {
#pragma unroll
    for (int c = 0; c < 4; ++c)
        __builtin_amdgcn_global_load_lds(
            (const __attribute__((address_space(1))) uint32_t*)(gslot + c * 256 + l * 4),
            (__attribute__((address_space(3))) uint32_t*)(stg + c * 256),
            16, 0, 0x11);
}
// Async flag fetch: sc0|sc1 global_load_lds of one dword.
__device__ __forceinline__ void flag_dma(const int* fp, int* stgf) {
    __builtin_amdgcn_global_load_lds(
        (const __attribute__((address_space(1))) uint32_t*)fp,
        (__attribute__((address_space(3))) uint32_t*)stgf, 4, 0, 0x11);
}

// Last wave's own-state pairs (elements 2l+128j, 2l+1+128j) via shuffles.
__device__ __forceinline__ void make_pairs(const float* hv, v2f* c7, int l) {
    const int s0 = (2 * l) & 63, s1 = (2 * l + 1) & 63;
    const bool hi = (l >= 32);
#pragma unroll
    for (int j = 0; j < 8; ++j) {
        float x0 = __shfl(hv[2 * j], s0, 64);
        float x1 = __shfl(hv[2 * j + 1], s0, 64);
        float y0 = __shfl(hv[2 * j], s1, 64);
        float y1 = __shfl(hv[2 * j + 1], s1, 64);
        c7[j].x = hi ? x1 : x0;
        c7[j].y = hi ? y1 : y0;
    }
}

// ---------------------------------------------------------------------------
// GEMM: out = relu(A @ W + bias), 1024^3, 64x64 tiles, global->reg prefetch.
// (R4 config -- 64x32 retile was measured neutral, reverted.)
// GATHER variant also re-initializes the scan flag arrays.
// ---------------------------------------------------------------------------
template <bool GATHER>
__global__ __launch_bounds__(256) void gemm_relu_kernel(
    const float* __restrict__ A, const int* __restrict__ labels,
    const float* __restrict__ emb, const float* __restrict__ W,
    const float* __restrict__ bias, float* __restrict__ out,
    int* __restrict__ prodG, int* __restrict__ consG)
{
    __shared__ float As[16][68];
    __shared__ float Bs[16][64];
    __shared__ int   lab[64];

    const int tid = threadIdx.x;
    const int bx = blockIdx.x & 15;
    const int by = blockIdx.x >> 4;
    const int m0 = by * 64, n0 = bx * 64;

    if (GATHER && blockIdx.x == 0) {
        if (tid < NBLK_SCAN) prodG[tid * 32] = -2;
        else if (tid < 2 * NBLK_SCAN) consG[(tid - NBLK_SCAN) * 32] = -2;
    }
    if (GATHER && tid < 64) lab[tid] = labels[m0 + tid];
    __syncthreads();

    const int tx = tid & 15, ty = tid >> 4;
    const int mload = tid >> 2;
    const int kq    = (tid & 3) * 4;
    const int kb    = tid >> 4;
    const int nb    = (tid & 15) * 4;

    const float* aBase;
    if (GATHER) aBase = emb + (size_t)lab[mload] * 1024 + kq;
    else        aBase = A   + (size_t)(m0 + mload) * 1024 + kq;
    const float* bBase = W + (size_t)kb * 1024 + n0 + nb;

    float4 a_pre = *(const float4*)aBase;
    float4 b_pre = *(const float4*)bBase;

    float acc[4][4] = {};

    for (int k0 = 0; k0 < 1024; k0 += 16) {
        As[kq + 0][mload] = a_pre.x;
        As[kq + 1][mload] = a_pre.y;
        As[kq + 2][mload] = a_pre.z;
        As[kq + 3][mload] = a_pre.w;
        *(float4*)&Bs[kb][nb] = b_pre;
        __syncthreads();

        if (k0 + 16 < 1024) {   // prefetch next tile while computing this one
            a_pre = *(const float4*)(aBase + k0 + 16);
            b_pre = *(const float4*)(bBase + (size_t)(k0 + 16) * 1024);
        }

#pragma unroll
        for (int kk = 0; kk < 16; ++kk) {
            float a_[4];
#pragma unroll
            for (int i = 0; i < 4; ++i) a_[i] = As[kk][ty * 4 + i];
            float4 bv = *(const float4*)&Bs[kk][tx * 4];
            float b_[4] = {bv.x, bv.y, bv.z, bv.w};
#pragma unroll
            for (int i = 0; i < 4; ++i)
#pragma unroll
                for (int j = 0; j < 4; ++j)
                    acc[i][j] = fmaf(a_[i], b_[j], acc[i][j]);
        }
        __syncthreads();
    }

    float bias4[4];
#pragma unroll
    for (int j = 0; j < 4; ++j) bias4[j] = bias[n0 + tx * 4 + j];
#pragma unroll
    for (int i = 0; i < 4; ++i) {
        float4 o;
        o.x = fmaxf(acc[i][0] + bias4[0], 0.f);
        o.y = fmaxf(acc[i][1] + bias4[1], 0.f);
        o.z = fmaxf(acc[i][2] + bias4[2], 0.f);
        o.w = fmaxf(acc[i][3] + bias4[3], 0.f);
        *(float4*)&out[(size_t)(m0 + ty * 4 + i) * 1024 + n0 + tx * 4] = o;
    }
}

// ---------------------------------------------------------------------------
// Dataflow scan: 64 blocks x 1024 threads (16 waves = 16 rows). R4 protocol,
// 16-wave blocks: per-batch chain is 16 blocks (15 cross-hops) instead of 32
// (31 cross-hops). Cross-hop ~4-5 beats vs intra ~1 => halving cross count
// removes ~16x4 beats from each batch diagonal. LDS 131.5 KB (< 160 KB).
// ---------------------------------------------------------------------------
__global__ __launch_bounds__(1024, 1) void scan_kernel(
    const float* __restrict__ h0, float* __restrict__ hf,
    const float* __restrict__ Wsani, const float* __restrict__ bsani,
    const float* __restrict__ lnw, const float* __restrict__ lnb,
    float* __restrict__ gbuf, int* __restrict__ prodG, int* __restrict__ consG)
{
    __shared__ float ring[NWAVE - 1][2][H_DIM];   // 120 KB
    __shared__ float stg[2][H_DIM];               // 8 KB (wave 0, dbuf)
    __shared__ int   stgflag[64];                 // async flag landing zone
    __shared__ int prodL[NWAVE], consL[NWAVE];

    const int tid = threadIdx.x, w = tid >> 6, l = tid & 63;
    const int Bb = blockIdx.x;
    const int b = Bb >> 4, p = Bb & 15;           // 4 batches x 16 blocks
    const int t = NWAVE * p + w;
    const int row = b * S_LEN + t;
    const bool hasR = (p < 15);
    const int leftB = Bb - 1, rightB = Bb + 1;

    float w0c[16], w1c[16], bsr[16], lwc[16], lbc[16], hv[16];
#pragma unroll
    for (int i = 0; i < 16; ++i) {
        int h = l + 64 * i;
        w0c[i] = Wsani[2 * h]; w1c[i] = Wsani[2 * h + 1];
        bsr[i] = fmaxf(bsani[h], 0.f);   // relu(bias) precomputed, exact
        lwc[i] = lnw[h]; lbc[i] = lnb[h];
        hv[i] = h0[(size_t)row * H_DIM + h];
    }
    const float bsc_neg_ok = 0.f; (void)bsc_neg_ok;
    // active-path conv needs raw bias: recover it (bsani may be negative).
    float bsc[16];
#pragma unroll
    for (int i = 0; i < 16; ++i) bsc[i] = bsani[l + 64 * i];

    if (tid < NWAVE) { prodL[tid] = -2; consL[tid] = -2; }
    if (tid < 64) stgflag[tid] = -2;
    __syncthreads();

    v2f c7[8];
    if (w < NWAVE - 1) {
#pragma unroll
        for (int i = 0; i < 16; ++i) ring[w][1][l + 64 * i] = hv[i];
        lds_release_fence();
        if (l == 0) ((volatile int*)prodL)[w] = -1;
    } else {
        if (hasR)
            llc_store_row_nowait(
                gbuf + ((size_t)Bb * GDEPTH + (GDEPTH - 1)) * H_DIM + l, hv);
        make_pairs(hv, c7, l);
    }

    const float inv1024 = 1.f / 1024.f;
    int F = -2, pfL = -3, consCache = -2;
    float vv[16];

    for (int L = 0; L < S_LEN; ++L) {
        const bool active = (L < t);
        if (active) {
            v2f pv[8], cv[8];
            if (w == 0) {
                const int* fp = prodG + leftB * 32;
                // need: beat L-1 data (4 ops) + flag (1 op) landed; the consG
                // ack store (newest) may stay in flight.
                asm volatile("s_waitcnt vmcnt(1)" ::: "memory");
                {
                    int fa = ((volatile int*)stgflag)[0];   // lane-0 copy, bcast
                    if (fa > F) F = fa;
                }
                if (pfL != L - 1) {   // catch-up path (cold)
                    while (F < L - 1) {
                        F = __builtin_amdgcn_readfirstlane(llc_load_int(fp));
                        if (F < L - 1) __builtin_amdgcn_s_sleep(1);
                    }
                    dma_slot(gbuf + ((size_t)leftB * GDEPTH +
                                     ((L - 1) & (GDEPTH - 1))) * H_DIM,
                             stg[(L - 1) & 1], l);
                    pfL = L - 1;
                    asm volatile("s_waitcnt vmcnt(0)" ::: "memory");
                }
                const float* srcp = stg[(L - 1) & 1];
#pragma unroll
                for (int j = 0; j < 8; ++j)
                    pv[j] = *(const v2f*)&srcp[2 * l + 128 * j];
#pragma unroll
                for (int j = 0; j < 8; ++j)
                    cv[j] = *(const v2f*)&ring[0][(L - 1) & 1][2 * l + 128 * j];
                if (L < t - 1) {
                    if (F >= L) {   // prefetch next beat into the OTHER buffer
                        dma_slot(gbuf + ((size_t)leftB * GDEPTH +
                                         (L & (GDEPTH - 1))) * H_DIM,
                                 stg[L & 1], l);
                        pfL = L;
                    }
                    flag_dma(fp, stgflag);  // async refresh for next step
                }
                llc_store_int(consG + Bb * 32, L);  // fire & forget
            } else {
                int spin = 0;
                while (((volatile int*)prodL)[w - 1] < L - 1)
                    { if (++spin > 8) __builtin_amdgcn_s_sleep(1); }
                const float* srcp = &ring[w - 1][(L - 1) & 1][0];
#pragma unroll
                for (int j = 0; j < 8; ++j)
                    pv[j] = *(const v2f*)&srcp[2 * l + 128 * j];
                if (w < NWAVE - 1) {
                    const float* srcc = &ring[w][(L - 1) & 1][0];
#pragma unroll
                    for (int j = 0; j < 8; ++j)
                        cv[j] = *(const v2f*)&srcc[2 * l + 128 * j];
                } else {
#pragma unroll
                    for (int j = 0; j < 8; ++j) cv[j] = c7[j];
                }
                if (l == 0) ((volatile int*)consL)[w] = L - 1;
            }
#pragma unroll
            for (int i = 0; i < 8; ++i) {
                float s = fmaf(pv[i].x, w0c[i], fmaf(pv[i].y, w1c[i], bsc[i]));
                s = fmaxf(s, 0.f);
                vv[i] = fmaf(DOMC, s, hv[i]);
            }
#pragma unroll
            for (int i = 8; i < 16; ++i) {
                float s = fmaf(cv[i - 8].x, w0c[i],
                               fmaf(cv[i - 8].y, w1c[i], bsc[i]));
                s = fmaxf(s, 0.f);
                vv[i] = fmaf(DOMC, s, hv[i]);
            }
        } else {
#pragma unroll
            for (int i = 0; i < 16; ++i)
                vv[i] = fmaf(DOMC, bsr[i], hv[i]);   // same fused op as before
        }
        float sum = 0.f, ss = 0.f;
#pragma unroll
        for (int i = 0; i < 16; ++i) { sum += vv[i]; ss = fmaf(vv[i], vv[i], ss); }
        sum = wave_reduce_sum(sum); ss = wave_reduce_sum(ss);
        const float mu = sum * inv1024;
        const float var = fmaf(-mu, mu, ss * inv1024);
        const float r = 1.f / sqrtf(var + EPS_LN);
#pragma unroll
        for (int i = 0; i < 16; ++i)
            hv[i] = fmaf((vv[i] - mu) * r, lwc[i], lbc[i]);

        if (active) {
            if (w < NWAVE - 1) {
                if (L >= 1) {
                    int spin = 0;
                    while (((volatile int*)consL)[w + 1] < L - 2)
                        { if (++spin > 8) __builtin_amdgcn_s_sleep(1); }
                }
#pragma unroll
                for (int i = 0; i < 16; ++i) ring[w][L & 1][l + 64 * i] = hv[i];
                lds_release_fence();
                if (l == 0) ((volatile int*)prodL)[w] = L;
            } else {
                if (hasR) {
                    if (consCache < L - (GDEPTH - 3)) {
                        int c = llc_load_int(consG + rightB * 32);
                        while (c < L - (GDEPTH - 1)) {
                            __builtin_amdgcn_s_sleep(1);
                            c = llc_load_int(consG + rightB * 32);
                        }
                        consCache = __builtin_amdgcn_readfirstlane(c);
                    }
                    llc_publish_lag1(
                        gbuf + ((size_t)Bb * GDEPTH + (L & (GDEPTH - 1))) * H_DIM + l,
                        prodG + Bb * 32, L - 1, hv);
                }
                if (L + 1 < t) make_pairs(hv, c7, l);
            }
        } else if (w == NWAVE - 1 && hasR && L == t) {
            llc_release(prodG + Bb * 32, t - 1);   // trailing flag release
        }
    }
#pragma unroll
    for (int i = 0; i < 16; ++i)
        hf[(size_t)row * H_DIM + l + 64 * i] = hv[i];
}

// ---------------------------------------------------------------------------
// Loss stage 1: per-(b,e) logsumexp over S, coalesced tile loads.
// ---------------------------------------------------------------------------
__global__ __launch_bounds__(256) void lse_kernel(
    const float* __restrict__ y, float* __restrict__ lse)
{
    const int b = blockIdx.x >> 4, et = blockIdx.x & 15;
    const int col = threadIdx.x & 63, rg = threadIdx.x >> 6;
    const int e = et * 64 + col;
    const float* yb = y + (size_t)b * S_LEN * H_DIM + e;
    float m = -INFINITY, s = 0.f;
    for (int r = rg; r < S_LEN; r += 4) {
        float v = yb[(size_t)r * H_DIM];
        float mn = fmaxf(m, v);
        s = fmaf(s, expf(m - mn), expf(v - mn));
        m = mn;
    }
    __shared__ float sm[4][64], sp[4][64];
    sm[rg][col] = m; sp[rg][col] = s;
    __syncthreads();
    if (threadIdx.x < 64) {
        const int c = threadIdx.x;
        float M = fmaxf(fmaxf(sm[0][c], sm[1][c]), fmaxf(sm[2][c], sm[3][c]));
        float S = sp[0][c] * expf(sm[0][c] - M) + sp[1][c] * expf(sm[1][c] - M)
                + sp[2][c] * expf(sm[2][c] - M) + sp[3][c] * expf(sm[3][c] - M);
        lse[b * H_DIM + et * 64 + c] = M + logf(S);
    }
}

__global__ __launch_bounds__(256) void loss_row_kernel(
    const float* __restrict__ y, const int* __restrict__ labels,
    const float* __restrict__ emb, const float* __restrict__ lse,
    float* __restrict__ partials)
{
    const int bs = blockIdx.x;
    const int b = bs >> 8;
    const int lab = labels[bs];
    const float* yr = y + (size_t)bs * H_DIM;
    const float* er = emb + (size_t)lab * H_DIM;
    const float* lr = lse + b * H_DIM;
    float acc = 0.f;
#pragma unroll
    for (int i = 0; i < 4; ++i) {
        int e = threadIdx.x + 256 * i;
        acc = fmaf(er[e], yr[e] - lr[e], acc);
    }
    acc = wave_reduce_sum(acc);
    __shared__ float wsum[4];
    if ((threadIdx.x & 63) == 0) wsum[threadIdx.x >> 6] = acc;
    __syncthreads();
    if (threadIdx.x == 0)
        partials[bs] = (wsum[0] + wsum[1]) + (wsum[2] + wsum[3]);
}

__global__ __launch_bounds__(256) void loss_final_kernel(
    const float* __restrict__ partials, float* __restrict__ out)
{
    const int tid = threadIdx.x;
    float a = 0.f;
#pragma unroll
    for (int j = 0; j < 4; ++j) a += partials[tid + 256 * j];
    a = wave_reduce_sum(a);
    __shared__ float wsum[4];
    if ((tid & 63) == 0) wsum[tid >> 6] = a;
    __syncthreads();
    if (tid == 0)
        out[0] = -((wsum[0] + wsum[1]) + (wsum[2] + wsum[3])) * (1.f / 4096.f);
}

// ---------------------------------------------------------------------------
extern "C" void kernel_launch(void* const* d_in, const int* in_sizes, int n_in,
                              void* d_out, int out_size, void* d_ws, size_t ws_size,
                              hipStream_t stream)
{
    const int*   labels = (const int*)  d_in[0];
    const float* emb    = (const float*)d_in[1];
    const float* W_in   = (const float*)d_in[2];
    const float* b_in   = (const float*)d_in[3];
    const float* W_sani = (const float*)d_in[4];
    const float* b_sani = (const float*)d_in[5];
    const float* ln_w   = (const float*)d_in[6];
    const float* ln_b   = (const float*)d_in[7];
    const float* W_out  = (const float*)d_in[8];
    const float* b_out  = (const float*)d_in[9];
    float* out = (float*)d_out;

    float* ws = (float*)d_ws;
    float* h0       = ws;                    // 1M floats
    float* hf       = ws + (1 << 20);        // 1M
    float* yb       = ws + 2 * (1 << 20);    // 1M
    float* gbuf     = ws + 3 * (1 << 20);    // 64*16*1024 = 1M (2M reserved)
    float* lse      = ws + 5 * (1 << 20);    // 4096
    float* partials = lse + 4096;            // 1024
    int*   prodG    = (int*)(partials + 1024);   // 64*32 ints
    int*   consG    = prodG + NBLK_SCAN * 32;

    gemm_relu_kernel<true><<<dim3(256), dim3(256), 0, stream>>>(
        nullptr, labels, emb, W_in, b_in, h0, prodG, consG);
    {
        const float* a_h0 = h0; float* a_hf = hf;
        const float* a_ws = W_sani; const float* a_bs = b_sani;
        const float* a_lw = ln_w;   const float* a_lb = ln_b;
        float* a_gb = gbuf; int* a_pf = prodG; int* a_cf = consG;
        void* args[] = { (void*)&a_h0, (void*)&a_hf, (void*)&a_ws, (void*)&a_bs,
                         (void*)&a_lw, (void*)&a_lb, (void*)&a_gb,
                         (void*)&a_pf, (void*)&a_cf };
        hipLaunchCooperativeKernel((const void*)scan_kernel,
                                   dim3(NBLK_SCAN), dim3(1024), args, 0, stream);
    }
    gemm_relu_kernel<false><<<dim3(256), dim3(256), 0, stream>>>(
        hf, nullptr, emb, W_out, b_out, yb, nullptr, nullptr);
    lse_kernel<<<dim3(64), dim3(256), 0, stream>>>(yb, lse);
    loss_row_kernel<<<dim3(1024), dim3(256), 0, stream>>>(
        yb, labels, emb, lse, partials);
    loss_final_kernel<<<dim3(1), dim3(256), 0, stream>>>(partials, out);
}

// Round 7
// 871.182 us; speedup vs baseline: 1.8585x; 1.8585x over previous
//
#include <hip/hip_runtime.h>
#include <cstdint>

#define H_DIM 1024
#define S_LEN 256
#define NBLK_SCAN 128
#define GRID_BLKS 256
#define GDEPTH 16
#define DOMC ((float)(1.0 - 0.9))
#define EPS_LN 1e-5f

typedef float v2f __attribute__((ext_vector_type(2)));

// ---------------------------------------------------------------------------
// DPP 64-lane all-reduce sum.
// ---------------------------------------------------------------------------
template <int CTRL, int RMASK, bool BC>
__device__ __forceinline__ float dpp_term(float x) {
    return __int_as_float(__builtin_amdgcn_update_dpp(
        0, __float_as_int(x), CTRL, RMASK, 0xf, BC));
}
__device__ __forceinline__ float wave_reduce_sum(float x) {
    x += dpp_term<0x111, 0xf, true>(x);
    x += dpp_term<0x112, 0xf, true>(x);
    x += dpp_term<0x114, 0xf, true>(x);
    x += dpp_term<0x118, 0xf, true>(x);
    x += dpp_term<0x142, 0xa, false>(x);
    x += dpp_term<0x143, 0xc, false>(x);
    return __int_as_float(__builtin_amdgcn_readlane(__float_as_int(x), 63));
}

// LDS-only release: order ring-data ds_writes before the flag ds_write.
__device__ __forceinline__ void lds_release_fence() {
    asm volatile("s_waitcnt lgkmcnt(0)" ::: "memory");
}

// ---------------------------------------------------------------------------
// MALL-coherent (sc0 sc1) global ops.
// ---------------------------------------------------------------------------
__device__ __forceinline__ int llc_load_int(const int* p) {
    int v;
    asm volatile("global_load_dword %0, %1, off sc0 sc1\n\ts_waitcnt vmcnt(0)"
                 : "=v"(v) : "v"(p) : "memory");
    return v;
}
__device__ __forceinline__ void llc_store_int(int* p, int v) {
    asm volatile("global_store_dword %0, %1, off sc0 sc1" :: "v"(p), "v"(v)
                 : "memory");
}
__device__ __forceinline__ void llc_store_row_nowait(float* base, const float* h) {
    asm volatile(
        "global_store_dword %16, %0, off sc0 sc1\n\t"
        "global_store_dword %16, %1, off offset:256 sc0 sc1\n\t"
        "global_store_dword %16, %2, off offset:512 sc0 sc1\n\t"
        "global_store_dword %16, %3, off offset:768 sc0 sc1\n\t"
        "global_store_dword %16, %4, off offset:1024 sc0 sc1\n\t"
        "global_store_dword %16, %5, off offset:1280 sc0 sc1\n\t"
        "global_store_dword %16, %6, off offset:1536 sc0 sc1\n\t"
        "global_store_dword %16, %7, off offset:1792 sc0 sc1\n\t"
        "global_store_dword %16, %8, off offset:2048 sc0 sc1\n\t"
        "global_store_dword %16, %9, off offset:2304 sc0 sc1\n\t"
        "global_store_dword %16, %10, off offset:2560 sc0 sc1\n\t"
        "global_store_dword %16, %11, off offset:2816 sc0 sc1\n\t"
        "global_store_dword %16, %12, off offset:3072 sc0 sc1\n\t"
        "global_store_dword %16, %13, off offset:3328 sc0 sc1\n\t"
        "global_store_dword %16, %14, off offset:3584 sc0 sc1\n\t"
        "global_store_dword %16, %15, off offset:3840 sc0 sc1"
        :: "v"(h[0]), "v"(h[1]), "v"(h[2]), "v"(h[3]),
           "v"(h[4]), "v"(h[5]), "v"(h[6]), "v"(h[7]),
           "v"(h[8]), "v"(h[9]), "v"(h[10]), "v"(h[11]),
           "v"(h[12]), "v"(h[13]), "v"(h[14]), "v"(h[15]), "v"(base)
        : "memory");
}
// Flag-lag-1 publish: beat-L data first, vmcnt(16) (drains beat L-1's 16 stores
// + old flag: 17 vmem ops/step, in-order retirement), then release flag L-1.
__device__ __forceinline__ void llc_publish_lag1(float* dbase, int* flagp,
                                                 int flagval, const float* h) {
    asm volatile(
        "global_store_dword %16, %0, off sc0 sc1\n\t"
        "global_store_dword %16, %1, off offset:256 sc0 sc1\n\t"
        "global_store_dword %16, %2, off offset:512 sc0 sc1\n\t"
        "global_store_dword %16, %3, off offset:768 sc0 sc1\n\t"
        "global_store_dword %16, %4, off offset:1024 sc0 sc1\n\t"
        "global_store_dword %16, %5, off offset:1280 sc0 sc1\n\t"
        "global_store_dword %16, %6, off offset:1536 sc0 sc1\n\t"
        "global_store_dword %16, %7, off offset:1792 sc0 sc1\n\t"
        "global_store_dword %16, %8, off offset:2048 sc0 sc1\n\t"
        "global_store_dword %16, %9, off offset:2304 sc0 sc1\n\t"
        "global_store_dword %16, %10, off offset:2560 sc0 sc1\n\t"
        "global_store_dword %16, %11, off offset:2816 sc0 sc1\n\t"
        "global_store_dword %16, %12, off offset:3072 sc0 sc1\n\t"
        "global_store_dword %16, %13, off offset:3328 sc0 sc1\n\t"
        "global_store_dword %16, %14, off offset:3584 sc0 sc1\n\t"
        "global_store_dword %16, %15, off offset:3840 sc0 sc1\n\t"
        "s_waitcnt vmcnt(16)\n\t"
        "global_store_dword %17, %18, off sc0 sc1"
        :: "v"(h[0]), "v"(h[1]), "v"(h[2]), "v"(h[3]),
           "v"(h[4]), "v"(h[5]), "v"(h[6]), "v"(h[7]),
           "v"(h[8]), "v"(h[9]), "v"(h[10]), "v"(h[11]),
           "v"(h[12]), "v"(h[13]), "v"(h[14]), "v"(h[15]),
           "v"(dbase), "v"(flagp), "v"(flagval)
        : "memory");
}
__device__ __forceinline__ void llc_release(int* flagp, int flagval) {
    asm volatile("s_waitcnt vmcnt(0)\n\t"
                 "global_store_dword %0, %1, off sc0 sc1"
                 :: "v"(flagp), "v"(flagval) : "memory");
}

// Async DMA of one 4 KB ring slot (global -> LDS staging), MALL-coherent.
__device__ __forceinline__ void dma_slot(const float* gslot, float* stg, int l) {
#pragma unroll
    for (int c = 0; c < 4; ++c)
        __builtin_amdgcn_global_load_lds(
            (const __attribute__((address_space(1))) uint32_t*)(gslot + c * 256 + l * 4),
            (__attribute__((address_space(3))) uint32_t*)(stg + c * 256),
            16, 0, 0x11);
}
__device__ __forceinline__ void flag_dma(const int* fp, int* stgf) {
    __builtin_amdgcn_global_load_lds(
        (const __attribute__((address_space(1))) uint32_t*)fp,
        (__attribute__((address_space(3))) uint32_t*)stgf, 4, 0, 0x11);
}

// Wave's own-state pairs (elements 2l+128j, 2l+1+128j) via shuffles.
__device__ __forceinline__ void make_pairs(const float* hv, v2f* c7, int l) {
    const int s0 = (2 * l) & 63, s1 = (2 * l + 1) & 63;
    const bool hi = (l >= 32);
#pragma unroll
    for (int j = 0; j < 8; ++j) {
        float x0 = __shfl(hv[2 * j], s0, 64);
        float x1 = __shfl(hv[2 * j + 1], s0, 64);
        float y0 = __shfl(hv[2 * j], s1, 64);
        float y1 = __shfl(hv[2 * j + 1], s1, 64);
        c7[j].x = hi ? x1 : x0;
        c7[j].y = hi ? y1 : y0;
    }
}

// ---------------------------------------------------------------------------
// Shared-memory union: phases reuse the same 66 KB.
// ---------------------------------------------------------------------------
struct SmemScan {
    float ring[7][2][H_DIM];   // 56 KB
    float stg[2][H_DIM];       // 8 KB
    int   stgflag[64];
    int   prodL[8], consL[8];
};
struct SmemGemm { int lab[64]; float As[16][68]; float Bs[16][68]; };
struct SmemLse  { float sm4[4][64]; float sp4[4][64]; };
struct SmemLoss { float wsum[2][4]; };
union Smem { SmemScan s; SmemGemm g; SmemLse l; SmemLoss r; };

// ---------------------------------------------------------------------------
// DIY grid barrier: release fence (wbl2) -> device-scope atomic arrive ->
// MALL-coherent poll -> acquire fence (inv). Counter is monotonic (no reset);
// host memsets it to 0 before launch.
// ---------------------------------------------------------------------------
__device__ __forceinline__ void grid_barrier(int* gbar, int target) {
    __syncthreads();
    if (threadIdx.x == 0) {
        __threadfence();                 // agent release: drain + wbl2 sc1
        atomicAdd(gbar, 1);
        while (llc_load_int(gbar) < target)
            __builtin_amdgcn_s_sleep(8);
        __threadfence();                 // agent acquire: inv sc0 sc1
    }
    __syncthreads();
}

// ---------------------------------------------------------------------------
// GEMM phase: out = relu(A @ W + bias), 1024^3, 64x64 tiles, 256 blocks x 512
// threads (2 rows x 4 cols per thread). Per-element FMA chain over k is in
// identical order to the R4 standalone kernel -> bit-identical output.
// ---------------------------------------------------------------------------
template <bool GATHER>
__device__ void gemm_phase(Smem& sm, const float* __restrict__ A,
                           const int* __restrict__ labels,
                           const float* __restrict__ emb,
                           const float* __restrict__ W,
                           const float* __restrict__ bias,
                           float* __restrict__ outp)
{
    const int tid = threadIdx.x;
    const int bx = blockIdx.x & 15;
    const int by = blockIdx.x >> 4;
    const int m0 = by * 64, n0 = bx * 64;

    if (GATHER && tid < 64) sm.g.lab[tid] = labels[m0 + tid];
    __syncthreads();

    const int arow = tid >> 3;           // 64 rows
    const int akp  = (tid & 7) * 2;      // 16 k, float2
    const int kb   = tid >> 5;           // 16 k-rows
    const int nb   = (tid & 31) * 2;     // 64 n, float2

    const float* aBase;
    if (GATHER) aBase = emb + (size_t)sm.g.lab[arow] * 1024 + akp;
    else        aBase = A   + (size_t)(m0 + arow) * 1024 + akp;
    const float* bBase = W + (size_t)kb * 1024 + n0 + nb;

    float2 a_pre = *(const float2*)aBase;
    float2 b_pre = *(const float2*)bBase;

    const int tx = tid & 15;             // 16 x 4 = 64 cols
    const int ty = tid >> 4;             // 32 x 2 = 64 rows
    float acc[2][4] = {};

    for (int k0 = 0; k0 < 1024; k0 += 16) {
        sm.g.As[akp + 0][arow] = a_pre.x;
        sm.g.As[akp + 1][arow] = a_pre.y;
        *(float2*)&sm.g.Bs[kb][nb] = b_pre;
        __syncthreads();

        if (k0 + 16 < 1024) {
            a_pre = *(const float2*)(aBase + k0 + 16);
            b_pre = *(const float2*)(bBase + (size_t)(k0 + 16) * 1024);
        }

#pragma unroll
        for (int kk = 0; kk < 16; ++kk) {
            float a_[2];
#pragma unroll
            for (int i = 0; i < 2; ++i) a_[i] = sm.g.As[kk][ty * 2 + i];
            float4 bv = *(const float4*)&sm.g.Bs[kk][tx * 4];
            float b_[4] = {bv.x, bv.y, bv.z, bv.w};
#pragma unroll
            for (int i = 0; i < 2; ++i)
#pragma unroll
                for (int j = 0; j < 4; ++j)
                    acc[i][j] = fmaf(a_[i], b_[j], acc[i][j]);
        }
        __syncthreads();
    }

    float bias4[4];
#pragma unroll
    for (int j = 0; j < 4; ++j) bias4[j] = bias[n0 + tx * 4 + j];
#pragma unroll
    for (int i = 0; i < 2; ++i) {
        float4 o;
        o.x = fmaxf(acc[i][0] + bias4[0], 0.f);
        o.y = fmaxf(acc[i][1] + bias4[1], 0.f);
        o.z = fmaxf(acc[i][2] + bias4[2], 0.f);
        o.w = fmaxf(acc[i][3] + bias4[3], 0.f);
        *(float4*)&outp[(size_t)(m0 + ty * 2 + i) * 1024 + n0 + tx * 4] = o;
    }
}

// ---------------------------------------------------------------------------
// Scan phase: R4's kernel body verbatim (blocks < 128 active).
// ---------------------------------------------------------------------------
__device__ void scan_phase(Smem& smu,
    const float* __restrict__ h0, float* __restrict__ hf,
    const float* __restrict__ Wsani, const float* __restrict__ bsani,
    const float* __restrict__ lnw, const float* __restrict__ lnb,
    float* __restrict__ gbuf, int* __restrict__ prodG, int* __restrict__ consG)
{
    auto& ring = smu.s.ring;
    auto& stg = smu.s.stg;
    auto& stgflag = smu.s.stgflag;
    auto& prodL = smu.s.prodL;
    auto& consL = smu.s.consL;

    const int tid = threadIdx.x, w = tid >> 6, l = tid & 63;
    const int Bb = blockIdx.x;
    const int b = Bb >> 5, p = Bb & 31;
    const int t = 8 * p + w;
    const int row = b * S_LEN + t;
    const bool hasR = (p < 31);
    const int leftB = Bb - 1, rightB = Bb + 1;

    float w0c[16], w1c[16], bsc[16], lwc[16], lbc[16], hv[16];
#pragma unroll
    for (int i = 0; i < 16; ++i) {
        int h = l + 64 * i;
        w0c[i] = Wsani[2 * h]; w1c[i] = Wsani[2 * h + 1];
        bsc[i] = bsani[h]; lwc[i] = lnw[h]; lbc[i] = lnb[h];
        hv[i] = h0[(size_t)row * H_DIM + h];
    }

    if (tid < 8)  { prodL[tid] = -2; consL[tid] = -2; }
    if (tid < 64) stgflag[tid] = -2;
    __syncthreads();

    v2f c7[8];
    if (w < 7) {
#pragma unroll
        for (int i = 0; i < 16; ++i) ring[w][1][l + 64 * i] = hv[i];
        lds_release_fence();
        if (l == 0) ((volatile int*)prodL)[w] = -1;
    } else {
        if (hasR)
            llc_store_row_nowait(
                gbuf + ((size_t)Bb * GDEPTH + (GDEPTH - 1)) * H_DIM + l, hv);
        make_pairs(hv, c7, l);
    }

    const float inv1024 = 1.f / 1024.f;
    int F = -2, pfL = -3, consCache = -2;
    float vv[16];

    for (int L = 0; L < S_LEN; ++L) {
        const bool active = (L < t);
        if (active) {
            v2f pv[8], cv[8];
            if (w == 0) {
                const int* fp = prodG + leftB * 32;
                asm volatile("s_waitcnt vmcnt(1)" ::: "memory");
                {
                    int fa = ((volatile int*)stgflag)[0];
                    if (fa > F) F = fa;
                }
                if (pfL != L - 1) {   // catch-up path (cold)
                    while (F < L - 1) {
                        F = __builtin_amdgcn_readfirstlane(llc_load_int(fp));
                        if (F < L - 1) __builtin_amdgcn_s_sleep(1);
                    }
                    dma_slot(gbuf + ((size_t)leftB * GDEPTH +
                                     ((L - 1) & (GDEPTH - 1))) * H_DIM,
                             stg[(L - 1) & 1], l);
                    pfL = L - 1;
                    asm volatile("s_waitcnt vmcnt(0)" ::: "memory");
                }
                const float* srcp = stg[(L - 1) & 1];
#pragma unroll
                for (int j = 0; j < 8; ++j)
                    pv[j] = *(const v2f*)&srcp[2 * l + 128 * j];
#pragma unroll
                for (int j = 0; j < 8; ++j)
                    cv[j] = *(const v2f*)&ring[0][(L - 1) & 1][2 * l + 128 * j];
                if (L < t - 1) {
                    if (F >= L) {
                        dma_slot(gbuf + ((size_t)leftB * GDEPTH +
                                         (L & (GDEPTH - 1))) * H_DIM,
                                 stg[L & 1], l);
                        pfL = L;
                    }
                    flag_dma(fp, stgflag);
                }
                llc_store_int(consG + Bb * 32, L);
            } else {
                int spin = 0;
                while (((volatile int*)prodL)[w - 1] < L - 1)
                    { if (++spin > 8) __builtin_amdgcn_s_sleep(1); }
                const float* srcp = &ring[w - 1][(L - 1) & 1][0];
#pragma unroll
                for (int j = 0; j < 8; ++j)
                    pv[j] = *(const v2f*)&srcp[2 * l + 128 * j];
                if (w < 7) {
                    const float* srcc = &ring[w][(L - 1) & 1][0];
#pragma unroll
                    for (int j = 0; j < 8; ++j)
                        cv[j] = *(const v2f*)&srcc[2 * l + 128 * j];
                } else {
#pragma unroll
                    for (int j = 0; j < 8; ++j) cv[j] = c7[j];
                }
                if (l == 0) ((volatile int*)consL)[w] = L - 1;
            }
#pragma unroll
            for (int i = 0; i < 8; ++i) {
                float s = fmaf(pv[i].x, w0c[i], fmaf(pv[i].y, w1c[i], bsc[i]));
                s = fmaxf(s, 0.f);
                vv[i] = fmaf(DOMC, s, hv[i]);
            }
#pragma unroll
            for (int i = 8; i < 16; ++i) {
                float s = fmaf(cv[i - 8].x, w0c[i],
                               fmaf(cv[i - 8].y, w1c[i], bsc[i]));
                s = fmaxf(s, 0.f);
                vv[i] = fmaf(DOMC, s, hv[i]);
            }
        } else {
#pragma unroll
            for (int i = 0; i < 16; ++i) {
                float s = fmaxf(bsc[i], 0.f);
                vv[i] = fmaf(DOMC, s, hv[i]);
            }
        }
        float sum = 0.f, ss = 0.f;
#pragma unroll
        for (int i = 0; i < 16; ++i) { sum += vv[i]; ss = fmaf(vv[i], vv[i], ss); }
        sum = wave_reduce_sum(sum); ss = wave_reduce_sum(ss);
        const float mu = sum * inv1024;
        const float var = fmaf(-mu, mu, ss * inv1024);
        const float r = 1.f / sqrtf(var + EPS_LN);
#pragma unroll
        for (int i = 0; i < 16; ++i)
            hv[i] = fmaf((vv[i] - mu) * r, lwc[i], lbc[i]);

        if (active) {
            if (w < 7) {
                if (L >= 1) {
                    int spin = 0;
                    while (((volatile int*)consL)[w + 1] < L - 2)
                        { if (++spin > 8) __builtin_amdgcn_s_sleep(1); }
                }
#pragma unroll
                for (int i = 0; i < 16; ++i) ring[w][L & 1][l + 64 * i] = hv[i];
                lds_release_fence();
                if (l == 0) ((volatile int*)prodL)[w] = L;
            } else {
                if (hasR) {
                    if (consCache < L - (GDEPTH - 3)) {
                        int c = llc_load_int(consG + rightB * 32);
                        while (c < L - (GDEPTH - 1)) {
                            __builtin_amdgcn_s_sleep(1);
                            c = llc_load_int(consG + rightB * 32);
                        }
                        consCache = __builtin_amdgcn_readfirstlane(c);
                    }
                    llc_publish_lag1(
                        gbuf + ((size_t)Bb * GDEPTH + (L & (GDEPTH - 1))) * H_DIM + l,
                        prodG + Bb * 32, L - 1, hv);
                }
                if (L + 1 < t) make_pairs(hv, c7, l);
            }
        } else if (w == 7 && hasR && L == t) {
            llc_release(prodG + Bb * 32, t - 1);
        }
    }
#pragma unroll
    for (int i = 0; i < 16; ++i)
        hf[(size_t)row * H_DIM + l + 64 * i] = hv[i];
}

// ---------------------------------------------------------------------------
// lse phase: exact replica of the 256-thread standalone kernel (blocks < 64;
// threads >= 256 idle).
// ---------------------------------------------------------------------------
__device__ void lse_phase(Smem& sm, const float* __restrict__ y,
                          float* __restrict__ lse)
{
    if (blockIdx.x >= 64) return;
    const int tid = threadIdx.x;
    const int b = blockIdx.x >> 4, et = blockIdx.x & 15;
    if (tid < 256) {
        const int col = tid & 63, rg = tid >> 6;
        const int e = et * 64 + col;
        const float* yb = y + (size_t)b * S_LEN * H_DIM + e;
        float m = -INFINITY, s = 0.f;
        for (int r = rg; r < S_LEN; r += 4) {
            float v = yb[(size_t)r * H_DIM];
            float mn = fmaxf(m, v);
            s = fmaf(s, expf(m - mn), expf(v - mn));
            m = mn;
        }
        sm.l.sm4[rg][col] = m; sm.l.sp4[rg][col] = s;
    }
    __syncthreads();
    if (tid < 64) {
        const int c = tid;
        float M = fmaxf(fmaxf(sm.l.sm4[0][c], sm.l.sm4[1][c]),
                        fmaxf(sm.l.sm4[2][c], sm.l.sm4[3][c]));
        float S = sm.l.sp4[0][c] * expf(sm.l.sm4[0][c] - M)
                + sm.l.sp4[1][c] * expf(sm.l.sm4[1][c] - M)
                + sm.l.sp4[2][c] * expf(sm.l.sm4[2][c] - M)
                + sm.l.sp4[3][c] * expf(sm.l.sm4[3][c] - M);
        lse[b * H_DIM + et * 64 + c] = M + logf(S);
    }
}

// ---------------------------------------------------------------------------
// Loss phase: 256 blocks x 4 rows. Two 256-thread groups each replicate the
// standalone loss_row pattern exactly (e = gt + 256*i, 4-wave combine).
// ---------------------------------------------------------------------------
__device__ void loss_phase(Smem& sm, const float* __restrict__ y,
                           const int* __restrict__ labels,
                           const float* __restrict__ emb,
                           const float* __restrict__ lseArr,
                           float* __restrict__ partials)
{
    const int tid = threadIdx.x;
    const int g = tid >> 8, gt = tid & 255;
#pragma unroll
    for (int it = 0; it < 2; ++it) {
        const int bs = blockIdx.x * 4 + it * 2 + g;
        const int b = bs >> 8;
        const int lab = labels[bs];
        const float* yr = y + (size_t)bs * H_DIM;
        const float* er = emb + (size_t)lab * H_DIM;
        const float* lr = lseArr + b * H_DIM;
        float acc = 0.f;
#pragma unroll
        for (int i = 0; i < 4; ++i) {
            int e = gt + 256 * i;
            acc = fmaf(er[e], yr[e] - lr[e], acc);
        }
        acc = wave_reduce_sum(acc);
        if ((gt & 63) == 0) sm.r.wsum[g][gt >> 6] = acc;
        __syncthreads();
        if (gt == 0)
            partials[bs] = (sm.r.wsum[g][0] + sm.r.wsum[g][1])
                         + (sm.r.wsum[g][2] + sm.r.wsum[g][3]);
        __syncthreads();
    }
}

__device__ void final_phase(Smem& sm, const float* __restrict__ partials,
                            float* __restrict__ outp)
{
    const int tid = threadIdx.x;
    float a = 0.f;
    if (tid < 256) {
#pragma unroll
        for (int j = 0; j < 4; ++j) a += partials[tid + 256 * j];
    }
    a = wave_reduce_sum(a);
    if (tid < 256 && (tid & 63) == 0) sm.r.wsum[0][tid >> 6] = a;
    __syncthreads();
    if (tid == 0)
        outp[0] = -((sm.r.wsum[0][0] + sm.r.wsum[0][1])
                  + (sm.r.wsum[0][2] + sm.r.wsum[0][3])) * (1.f / 4096.f);
}

// ---------------------------------------------------------------------------
// The fused pipeline: one cooperative launch, 256 blocks x 512 threads.
// ---------------------------------------------------------------------------
__global__ __launch_bounds__(512, 1) void fused_kernel(
    const int* __restrict__ labels, const float* __restrict__ emb,
    const float* __restrict__ W_in, const float* __restrict__ b_in,
    const float* __restrict__ W_sani, const float* __restrict__ b_sani,
    const float* __restrict__ ln_w, const float* __restrict__ ln_b,
    const float* __restrict__ W_out, const float* __restrict__ b_out,
    float* __restrict__ out,
    float* __restrict__ h0, float* __restrict__ hf, float* __restrict__ yb,
    float* __restrict__ gbuf, float* __restrict__ lse,
    float* __restrict__ partials, int* __restrict__ prodG,
    int* __restrict__ consG, int* __restrict__ gbar)
{
    __shared__ Smem sm;

    // P0: scan-flag init (block 0, MALL-coherent stores) + input GEMM (gather).
    if (blockIdx.x == 0) {
        if (threadIdx.x < NBLK_SCAN)
            llc_store_int(prodG + threadIdx.x * 32, -2);
        else if (threadIdx.x < 2 * NBLK_SCAN)
            llc_store_int(consG + (threadIdx.x - NBLK_SCAN) * 32, -2);
    }
    gemm_phase<true>(sm, nullptr, labels, emb, W_in, b_in, h0);
    grid_barrier(gbar, GRID_BLKS * 1);

    // P1: dataflow scan (blocks < 128).
    if (blockIdx.x < NBLK_SCAN)
        scan_phase(sm, h0, hf, W_sani, b_sani, ln_w, ln_b, gbuf, prodG, consG);
    grid_barrier(gbar, GRID_BLKS * 2);

    // P2: output GEMM.
    gemm_phase<false>(sm, hf, nullptr, emb, W_out, b_out, yb);
    grid_barrier(gbar, GRID_BLKS * 3);

    // P3: logsumexp over S (blocks < 64).
    lse_phase(sm, yb, lse);
    grid_barrier(gbar, GRID_BLKS * 4);

    // P4: per-row loss partials.
    loss_phase(sm, yb, labels, emb, lse, partials);
    grid_barrier(gbar, GRID_BLKS * 5);

    // P5: final reduction (block 0).
    if (blockIdx.x == 0) final_phase(sm, partials, out);
}

// ---------------------------------------------------------------------------
extern "C" void kernel_launch(void* const* d_in, const int* in_sizes, int n_in,
                              void* d_out, int out_size, void* d_ws, size_t ws_size,
                              hipStream_t stream)
{
    const int*   labels = (const int*)  d_in[0];
    const float* emb    = (const float*)d_in[1];
    const float* W_in   = (const float*)d_in[2];
    const float* b_in   = (const float*)d_in[3];
    const float* W_sani = (const float*)d_in[4];
    const float* b_sani = (const float*)d_in[5];
    const float* ln_w   = (const float*)d_in[6];
    const float* ln_b   = (const float*)d_in[7];
    const float* W_out  = (const float*)d_in[8];
    const float* b_out  = (const float*)d_in[9];
    float* out = (float*)d_out;

    float* ws = (float*)d_ws;
    float* h0       = ws;                    // 1M floats
    float* hf       = ws + (1 << 20);        // 1M
    float* yb       = ws + 2 * (1 << 20);    // 1M
    float* gbuf     = ws + 3 * (1 << 20);    // 128*16*1024 = 2M
    float* lse      = ws + 5 * (1 << 20);    // 4096
    float* partials = lse + 4096;            // 1024
    int*   prodG    = (int*)(partials + 1024);   // 128*32 ints
    int*   consG    = prodG + NBLK_SCAN * 32;
    int*   gbar     = consG + NBLK_SCAN * 32;

    hipMemsetAsync(gbar, 0, sizeof(int), stream);

    const int* a_lab = labels; const float* a_emb = emb;
    const float* a_wi = W_in; const float* a_bi = b_in;
    const float* a_ws = W_sani; const float* a_bs = b_sani;
    const float* a_lw = ln_w; const float* a_lb = ln_b;
    const float* a_wo = W_out; const float* a_bo = b_out;
    float* a_out = out;
    float* a_h0 = h0; float* a_hf = hf; float* a_yb = yb;
    float* a_gb = gbuf; float* a_lse = lse; float* a_pt = partials;
    int* a_pf = prodG; int* a_cf = consG; int* a_gbar = gbar;
    void* args[] = { (void*)&a_lab, (void*)&a_emb, (void*)&a_wi, (void*)&a_bi,
                     (void*)&a_ws, (void*)&a_bs, (void*)&a_lw, (void*)&a_lb,
                     (void*)&a_wo, (void*)&a_bo, (void*)&a_out,
                     (void*)&a_h0, (void*)&a_hf, (void*)&a_yb,
                     (void*)&a_gb, (void*)&a_lse, (void*)&a_pt,
                     (void*)&a_pf, (void*)&a_cf, (void*)&a_gbar };
    hipLaunchCooperativeKernel((const void*)fused_kernel,
                               dim3(GRID_BLKS), dim3(512), args, 0, stream);
}

// Round 8
// 689.291 us; speedup vs baseline: 2.3490x; 1.2639x over previous
//
#include <hip/hip_runtime.h>
#include <cstdint>

#define H_DIM 1024
#define S_LEN 256
#define NBLK_SCAN 128
#define GDEPTH 16
#define DOMC ((float)(1.0 - 0.9))
#define EPS_LN 1e-5f

typedef float v2f __attribute__((ext_vector_type(2)));

// ---------------------------------------------------------------------------
// DPP 64-lane all-reduce sum.
// ---------------------------------------------------------------------------
template <int CTRL, int RMASK, bool BC>
__device__ __forceinline__ float dpp_term(float x) {
    return __int_as_float(__builtin_amdgcn_update_dpp(
        0, __float_as_int(x), CTRL, RMASK, 0xf, BC));
}
__device__ __forceinline__ float wave_reduce_sum(float x) {
    x += dpp_term<0x111, 0xf, true>(x);
    x += dpp_term<0x112, 0xf, true>(x);
    x += dpp_term<0x114, 0xf, true>(x);
    x += dpp_term<0x118, 0xf, true>(x);
    x += dpp_term<0x142, 0xa, false>(x);
    x += dpp_term<0x143, 0xc, false>(x);
    return __int_as_float(__builtin_amdgcn_readlane(__float_as_int(x), 63));
}

// LDS-only release: order ring-data ds_writes before the flag ds_write.
// NOT __threadfence_block(): its vmcnt(0) would drain wave0's in-flight
// prefetch DMA every step (measured R0-R4).
__device__ __forceinline__ void lds_release_fence() {
    asm volatile("s_waitcnt lgkmcnt(0)" ::: "memory");
}

// ---------------------------------------------------------------------------
// MALL-coherent (sc0 sc1) global ops.
// ---------------------------------------------------------------------------
__device__ __forceinline__ int llc_load_int(const int* p) {
    int v;
    asm volatile("global_load_dword %0, %1, off sc0 sc1\n\ts_waitcnt vmcnt(0)"
                 : "=v"(v) : "v"(p) : "memory");
    return v;
}
__device__ __forceinline__ void llc_store_int(int* p, int v) {
    asm volatile("global_store_dword %0, %1, off sc0 sc1" :: "v"(p), "v"(v)
                 : "memory");
}
__device__ __forceinline__ void llc_store_row_nowait(float* base, const float* h) {
    asm volatile(
        "global_store_dword %16, %0, off sc0 sc1\n\t"
        "global_store_dword %16, %1, off offset:256 sc0 sc1\n\t"
        "global_store_dword %16, %2, off offset:512 sc0 sc1\n\t"
        "global_store_dword %16, %3, off offset:768 sc0 sc1\n\t"
        "global_store_dword %16, %4, off offset:1024 sc0 sc1\n\t"
        "global_store_dword %16, %5, off offset:1280 sc0 sc1\n\t"
        "global_store_dword %16, %6, off offset:1536 sc0 sc1\n\t"
        "global_store_dword %16, %7, off offset:1792 sc0 sc1\n\t"
        "global_store_dword %16, %8, off offset:2048 sc0 sc1\n\t"
        "global_store_dword %16, %9, off offset:2304 sc0 sc1\n\t"
        "global_store_dword %16, %10, off offset:2560 sc0 sc1\n\t"
        "global_store_dword %16, %11, off offset:2816 sc0 sc1\n\t"
        "global_store_dword %16, %12, off offset:3072 sc0 sc1\n\t"
        "global_store_dword %16, %13, off offset:3328 sc0 sc1\n\t"
        "global_store_dword %16, %14, off offset:3584 sc0 sc1\n\t"
        "global_store_dword %16, %15, off offset:3840 sc0 sc1"
        :: "v"(h[0]), "v"(h[1]), "v"(h[2]), "v"(h[3]),
           "v"(h[4]), "v"(h[5]), "v"(h[6]), "v"(h[7]),
           "v"(h[8]), "v"(h[9]), "v"(h[10]), "v"(h[11]),
           "v"(h[12]), "v"(h[13]), "v"(h[14]), "v"(h[15]), "v"(base)
        : "memory");
}
// Flag-lag-1 publish: issue beat-L data first, then vmcnt(16) (drains beat L-1's
// 16 stores + the old flag: 17 vmem ops/step, in-order retirement), then release
// flag L-1. No stall: the waited ops were issued a full step earlier.
__device__ __forceinline__ void llc_publish_lag1(float* dbase, int* flagp,
                                                 int flagval, const float* h) {
    asm volatile(
        "global_store_dword %16, %0, off sc0 sc1\n\t"
        "global_store_dword %16, %1, off offset:256 sc0 sc1\n\t"
        "global_store_dword %16, %2, off offset:512 sc0 sc1\n\t"
        "global_store_dword %16, %3, off offset:768 sc0 sc1\n\t"
        "global_store_dword %16, %4, off offset:1024 sc0 sc1\n\t"
        "global_store_dword %16, %5, off offset:1280 sc0 sc1\n\t"
        "global_store_dword %16, %6, off offset:1536 sc0 sc1\n\t"
        "global_store_dword %16, %7, off offset:1792 sc0 sc1\n\t"
        "global_store_dword %16, %8, off offset:2048 sc0 sc1\n\t"
        "global_store_dword %16, %9, off offset:2304 sc0 sc1\n\t"
        "global_store_dword %16, %10, off offset:2560 sc0 sc1\n\t"
        "global_store_dword %16, %11, off offset:2816 sc0 sc1\n\t"
        "global_store_dword %16, %12, off offset:3072 sc0 sc1\n\t"
        "global_store_dword %16, %13, off offset:3328 sc0 sc1\n\t"
        "global_store_dword %16, %14, off offset:3584 sc0 sc1\n\t"
        "global_store_dword %16, %15, off offset:3840 sc0 sc1\n\t"
        "s_waitcnt vmcnt(16)\n\t"
        "global_store_dword %17, %18, off sc0 sc1"
        :: "v"(h[0]), "v"(h[1]), "v"(h[2]), "v"(h[3]),
           "v"(h[4]), "v"(h[5]), "v"(h[6]), "v"(h[7]),
           "v"(h[8]), "v"(h[9]), "v"(h[10]), "v"(h[11]),
           "v"(h[12]), "v"(h[13]), "v"(h[14]), "v"(h[15]),
           "v"(dbase), "v"(flagp), "v"(flagval)
        : "memory");
}
__device__ __forceinline__ void llc_release(int* flagp, int flagval) {
    asm volatile("s_waitcnt vmcnt(0)\n\t"
                 "global_store_dword %0, %1, off sc0 sc1"
                 :: "v"(flagp), "v"(flagval) : "memory");
}

// Async DMA of one 4 KB ring slot (global -> LDS staging), MALL-coherent.
// aux 0x11 = SC0|SC1 (gfx940+ CPol encoding). vmcnt-tracked.
__device__ __forceinline__ void dma_slot(const float* gslot, float* stg, int l) {
#pragma unroll
    for (int c = 0; c < 4; ++c)
        __builtin_amdgcn_global_load_lds(
            (const __attribute__((address_space(1))) uint32_t*)(gslot + c * 256 + l * 4),
            (__attribute__((address_space(3))) uint32_t*)(stg + c * 256),
            16, 0, 0x11);
}
// Async flag fetch: sc0|sc1 global_load_lds of one dword.
__device__ __forceinline__ void flag_dma(const int* fp, int* stgf) {
    __builtin_amdgcn_global_load_lds(
        (const __attribute__((address_space(1))) uint32_t*)fp,
        (__attribute__((address_space(3))) uint32_t*)stgf, 4, 0, 0x11);
}

// Wave-7 own-state pairs (elements 2l+128j, 2l+1+128j) via shuffles.
__device__ __forceinline__ void make_pairs(const float* hv, v2f* c7, int l) {
    const int s0 = (2 * l) & 63, s1 = (2 * l + 1) & 63;
    const bool hi = (l >= 32);
#pragma unroll
    for (int j = 0; j < 8; ++j) {
        float x0 = __shfl(hv[2 * j], s0, 64);
        float x1 = __shfl(hv[2 * j + 1], s0, 64);
        float y0 = __shfl(hv[2 * j], s1, 64);
        float y1 = __shfl(hv[2 * j + 1], s1, 64);
        c7[j].x = hi ? x1 : x0;
        c7[j].y = hi ? y1 : y0;
    }
}

// ---------------------------------------------------------------------------
// GEMM: out = relu(A @ W + bias), 1024^3, 64x64 tiles, global->reg prefetch.
// As padded to [16][72]: row = 288 B (16B-aligned), so the inner loop reads
// one aligned ds_read_b128 instead of 4 scalar ds_read_b32 (the k-loop was
// LDS-throughput-bound: 35 -> 24 cy/kk/wave). Same values, same FMA order.
// GATHER variant also re-initializes the scan flag arrays.
// ---------------------------------------------------------------------------
template <bool GATHER>
__global__ __launch_bounds__(256) void gemm_relu_kernel(
    const float* __restrict__ A, const int* __restrict__ labels,
    const float* __restrict__ emb, const float* __restrict__ W,
    const float* __restrict__ bias, float* __restrict__ out,
    int* __restrict__ prodG, int* __restrict__ consG)
{
    __shared__ __align__(16) float As[16][72];
    __shared__ __align__(16) float Bs[16][64];
    __shared__ int   lab[64];

    const int tid = threadIdx.x;
    const int bx = blockIdx.x & 15;
    const int by = blockIdx.x >> 4;
    const int m0 = by * 64, n0 = bx * 64;

    if (GATHER && blockIdx.x == 0) {
        if (tid < NBLK_SCAN) prodG[tid * 32] = -2;
        else                 consG[(tid - NBLK_SCAN) * 32] = -2;
    }
    if (GATHER && tid < 64) lab[tid] = labels[m0 + tid];
    __syncthreads();

    const int tx = tid & 15, ty = tid >> 4;
    const int mload = tid >> 2;
    const int kq    = (tid & 3) * 4;
    const int kb    = tid >> 4;
    const int nb    = (tid & 15) * 4;

    const float* aBase;
    if (GATHER) aBase = emb + (size_t)lab[mload] * 1024 + kq;
    else        aBase = A   + (size_t)(m0 + mload) * 1024 + kq;
    const float* bBase = W + (size_t)kb * 1024 + n0 + nb;

    float4 a_pre = *(const float4*)aBase;
    float4 b_pre = *(const float4*)bBase;

    float acc[4][4] = {};

    for (int k0 = 0; k0 < 1024; k0 += 16) {
        // A staged transposed: As[k][m]
        As[kq + 0][mload] = a_pre.x;
        As[kq + 1][mload] = a_pre.y;
        As[kq + 2][mload] = a_pre.z;
        As[kq + 3][mload] = a_pre.w;
        *(float4*)&Bs[kb][nb] = b_pre;
        __syncthreads();

        if (k0 + 16 < 1024) {   // prefetch next tile while computing this one
            a_pre = *(const float4*)(aBase + k0 + 16);
            b_pre = *(const float4*)(bBase + (size_t)(k0 + 16) * 1024);
        }

#pragma unroll
        for (int kk = 0; kk < 16; ++kk) {
            float4 av = *(const float4*)&As[kk][ty * 4];
            float a_[4] = {av.x, av.y, av.z, av.w};
            float4 bv = *(const float4*)&Bs[kk][tx * 4];
            float b_[4] = {bv.x, bv.y, bv.z, bv.w};
#pragma unroll
            for (int i = 0; i < 4; ++i)
#pragma unroll
                for (int j = 0; j < 4; ++j)
                    acc[i][j] = fmaf(a_[i], b_[j], acc[i][j]);
        }
        __syncthreads();
    }

    float bias4[4];
#pragma unroll
    for (int j = 0; j < 4; ++j) bias4[j] = bias[n0 + tx * 4 + j];
#pragma unroll
    for (int i = 0; i < 4; ++i) {
        float4 o;
        o.x = fmaxf(acc[i][0] + bias4[0], 0.f);
        o.y = fmaxf(acc[i][1] + bias4[1], 0.f);
        o.z = fmaxf(acc[i][2] + bias4[2], 0.f);
        o.w = fmaxf(acc[i][3] + bias4[3], 0.f);
        *(float4*)&out[(size_t)(m0 + ty * 4 + i) * 1024 + n0 + tx * 4] = o;
    }
}

// ---------------------------------------------------------------------------
// Dataflow scan: 128 blocks x 512 threads (8 waves = 8 rows). R4 kernel
// verbatim (best measured: 330 us). Launched as a REGULAR kernel: 128 blocks
// x 66 KB LDS x 512 thr always fit co-resident on 256 CUs (stream-serialized,
// nothing competes), and dropping hipLaunchCooperativeKernel makes the whole
// 6-kernel sequence graph-capturable (R7 exposed ~250 us coop-launch host
// overhead per iteration).
// ---------------------------------------------------------------------------
__global__ __launch_bounds__(512, 1) void scan_kernel(
    const float* __restrict__ h0, float* __restrict__ hf,
    const float* __restrict__ Wsani, const float* __restrict__ bsani,
    const float* __restrict__ lnw, const float* __restrict__ lnb,
    float* __restrict__ gbuf, int* __restrict__ prodG, int* __restrict__ consG)
{
    __shared__ float ring[7][2][H_DIM];   // 56 KB
    __shared__ float stg[2][H_DIM];       // 8 KB DMA staging (wave 0, dbuf)
    __shared__ int   stgflag[64];         // async flag landing zone (wave 0)
    __shared__ int prodL[8], consL[8];

    const int tid = threadIdx.x, w = tid >> 6, l = tid & 63;
    const int Bb = blockIdx.x;
    const int b = Bb >> 5, p = Bb & 31;
    const int t = 8 * p + w;
    const int row = b * S_LEN + t;
    const bool hasR = (p < 31);
    const int leftB = Bb - 1, rightB = Bb + 1;

    float w0c[16], w1c[16], bsc[16], lwc[16], lbc[16], hv[16];
#pragma unroll
    for (int i = 0; i < 16; ++i) {
        int h = l + 64 * i;
        w0c[i] = Wsani[2 * h]; w1c[i] = Wsani[2 * h + 1];
        bsc[i] = bsani[h]; lwc[i] = lnw[h]; lbc[i] = lnb[h];
        hv[i] = h0[(size_t)row * H_DIM + h];
    }

    if (tid < 8)  { prodL[tid] = -2; consL[tid] = -2; }
    if (tid < 64) stgflag[tid] = -2;
    __syncthreads();

    v2f c7[8];
    if (w < 7) {
#pragma unroll
        for (int i = 0; i < 16; ++i) ring[w][1][l + 64 * i] = hv[i];
        lds_release_fence();
        if (l == 0) ((volatile int*)prodL)[w] = -1;
    } else {
        if (hasR)
            llc_store_row_nowait(
                gbuf + ((size_t)Bb * GDEPTH + (GDEPTH - 1)) * H_DIM + l, hv);
        make_pairs(hv, c7, l);
    }

    const float inv1024 = 1.f / 1024.f;
    int F = -2, pfL = -3, consCache = -2;
    float vv[16];

    for (int L = 0; L < S_LEN; ++L) {
        const bool active = (L < t);
        if (active) {
            v2f pv[8], cv[8];
            if (w == 0) {
                const int* fp = prodG + leftB * 32;
                // single wait covers: DMA(beat L-1), async flag -- issued ~one
                // full step ago; consG ack (newest) may stay in flight.
                asm volatile("s_waitcnt vmcnt(1)" ::: "memory");
                {
                    int fa = ((volatile int*)stgflag)[0];   // lane-0 copy, bcast
                    if (fa > F) F = fa;
                }
                if (pfL != L - 1) {   // catch-up path (cold)
                    while (F < L - 1) {
                        F = __builtin_amdgcn_readfirstlane(llc_load_int(fp));
                        if (F < L - 1) __builtin_amdgcn_s_sleep(1);
                    }
                    dma_slot(gbuf + ((size_t)leftB * GDEPTH +
                                     ((L - 1) & (GDEPTH - 1))) * H_DIM,
                             stg[(L - 1) & 1], l);
                    pfL = L - 1;
                    asm volatile("s_waitcnt vmcnt(0)" ::: "memory");
                }
                const float* srcp = stg[(L - 1) & 1];
#pragma unroll
                for (int j = 0; j < 8; ++j)
                    pv[j] = *(const v2f*)&srcp[2 * l + 128 * j];
#pragma unroll
                for (int j = 0; j < 8; ++j)
                    cv[j] = *(const v2f*)&ring[0][(L - 1) & 1][2 * l + 128 * j];
                if (L < t - 1) {
                    if (F >= L) {   // prefetch next beat into the OTHER buffer
                        dma_slot(gbuf + ((size_t)leftB * GDEPTH +
                                         (L & (GDEPTH - 1))) * H_DIM,
                                 stg[L & 1], l);
                        pfL = L;
                    }
                    flag_dma(fp, stgflag);  // async refresh for next step
                }
                llc_store_int(consG + Bb * 32, L);  // fire & forget
            } else {
                int spin = 0;
                while (((volatile int*)prodL)[w - 1] < L - 1)
                    { if (++spin > 8) __builtin_amdgcn_s_sleep(1); }
                const float* srcp = &ring[w - 1][(L - 1) & 1][0];
#pragma unroll
                for (int j = 0; j < 8; ++j)
                    pv[j] = *(const v2f*)&srcp[2 * l + 128 * j];
                if (w < 7) {
                    const float* srcc = &ring[w][(L - 1) & 1][0];
#pragma unroll
                    for (int j = 0; j < 8; ++j)
                        cv[j] = *(const v2f*)&srcc[2 * l + 128 * j];
                } else {
#pragma unroll
                    for (int j = 0; j < 8; ++j) cv[j] = c7[j];
                }
                if (l == 0) ((volatile int*)consL)[w] = L - 1;
            }
#pragma unroll
            for (int i = 0; i < 8; ++i) {
                float s = fmaf(pv[i].x, w0c[i], fmaf(pv[i].y, w1c[i], bsc[i]));
                s = fmaxf(s, 0.f);
                vv[i] = fmaf(DOMC, s, hv[i]);
            }
#pragma unroll
            for (int i = 8; i < 16; ++i) {
                float s = fmaf(cv[i - 8].x, w0c[i],
                               fmaf(cv[i - 8].y, w1c[i], bsc[i]));
                s = fmaxf(s, 0.f);
                vv[i] = fmaf(DOMC, s, hv[i]);
            }
        } else {
#pragma unroll
            for (int i = 0; i < 16; ++i) {
                float s = fmaxf(bsc[i], 0.f);
                vv[i] = fmaf(DOMC, s, hv[i]);
            }
        }
        float sum = 0.f, ss = 0.f;
#pragma unroll
        for (int i = 0; i < 16; ++i) { sum += vv[i]; ss = fmaf(vv[i], vv[i], ss); }
        sum = wave_reduce_sum(sum); ss = wave_reduce_sum(ss);
        const float mu = sum * inv1024;
        const float var = fmaf(-mu, mu, ss * inv1024);
        const float r = 1.f / sqrtf(var + EPS_LN);
#pragma unroll
        for (int i = 0; i < 16; ++i)
            hv[i] = fmaf((vv[i] - mu) * r, lwc[i], lbc[i]);

        if (active) {
            if (w < 7) {
                if (L >= 1) {
                    int spin = 0;
                    while (((volatile int*)consL)[w + 1] < L - 2)
                        { if (++spin > 8) __builtin_amdgcn_s_sleep(1); }
                }
#pragma unroll
                for (int i = 0; i < 16; ++i) ring[w][L & 1][l + 64 * i] = hv[i];
                lds_release_fence();
                if (l == 0) ((volatile int*)prodL)[w] = L;
            } else {
                if (hasR) {
                    if (consCache < L - (GDEPTH - 3)) {
                        int c = llc_load_int(consG + rightB * 32);
                        while (c < L - (GDEPTH - 1)) {
                            __builtin_amdgcn_s_sleep(1);
                            c = llc_load_int(consG + rightB * 32);
                        }
                        consCache = __builtin_amdgcn_readfirstlane(c);
                    }
                    llc_publish_lag1(
                        gbuf + ((size_t)Bb * GDEPTH + (L & (GDEPTH - 1))) * H_DIM + l,
                        prodG + Bb * 32, L - 1, hv);
                }
                if (L + 1 < t) make_pairs(hv, c7, l);
            }
        } else if (w == 7 && hasR && L == t) {
            llc_release(prodG + Bb * 32, t - 1);   // trailing flag release
        }
    }
#pragma unroll
    for (int i = 0; i < 16; ++i)
        hf[(size_t)row * H_DIM + l + 64 * i] = hv[i];
}

// ---------------------------------------------------------------------------
// Loss stage 1: per-(b,e) logsumexp over S, coalesced tile loads.
// ---------------------------------------------------------------------------
__global__ __launch_bounds__(256) void lse_kernel(
    const float* __restrict__ y, float* __restrict__ lse)
{
    const int b = blockIdx.x >> 4, et = blockIdx.x & 15;
    const int col = threadIdx.x & 63, rg = threadIdx.x >> 6;
    const int e = et * 64 + col;
    const float* yb = y + (size_t)b * S_LEN * H_DIM + e;
    float m = -INFINITY, s = 0.f;
    for (int r = rg; r < S_LEN; r += 4) {
        float v = yb[(size_t)r * H_DIM];
        float mn = fmaxf(m, v);
        s = fmaf(s, expf(m - mn), expf(v - mn));
        m = mn;
    }
    __shared__ float sm[4][64], sp[4][64];
    sm[rg][col] = m; sp[rg][col] = s;
    __syncthreads();
    if (threadIdx.x < 64) {
        const int c = threadIdx.x;
        float M = fmaxf(fmaxf(sm[0][c], sm[1][c]), fmaxf(sm[2][c], sm[3][c]));
        float S = sp[0][c] * expf(sm[0][c] - M) + sp[1][c] * expf(sm[1][c] - M)
                + sp[2][c] * expf(sm[2][c] - M) + sp[3][c] * expf(sm[3][c] - M);
        lse[b * H_DIM + et * 64 + c] = M + logf(S);
    }
}

__global__ __launch_bounds__(256) void loss_row_kernel(
    const float* __restrict__ y, const int* __restrict__ labels,
    const float* __restrict__ emb, const float* __restrict__ lse,
    float* __restrict__ partials)
{
    const int bs = blockIdx.x;
    const int b = bs >> 8;
    const int lab = labels[bs];
    const float* yr = y + (size_t)bs * H_DIM;
    const float* er = emb + (size_t)lab * H_DIM;
    const float* lr = lse + b * H_DIM;
    float acc = 0.f;
#pragma unroll
    for (int i = 0; i < 4; ++i) {
        int e = threadIdx.x + 256 * i;
        acc = fmaf(er[e], yr[e] - lr[e], acc);
    }
    acc = wave_reduce_sum(acc);
    __shared__ float wsum[4];
    if ((threadIdx.x & 63) == 0) wsum[threadIdx.x >> 6] = acc;
    __syncthreads();
    if (threadIdx.x == 0)
        partials[bs] = (wsum[0] + wsum[1]) + (wsum[2] + wsum[3]);
}

__global__ __launch_bounds__(256) void loss_final_kernel(
    const float* __restrict__ partials, float* __restrict__ out)
{
    const int tid = threadIdx.x;
    float a = 0.f;
#pragma unroll
    for (int j = 0; j < 4; ++j) a += partials[tid + 256 * j];
    a = wave_reduce_sum(a);
    __shared__ float wsum[4];
    if ((tid & 63) == 0) wsum[tid >> 6] = a;
    __syncthreads();
    if (tid == 0)
        out[0] = -((wsum[0] + wsum[1]) + (wsum[2] + wsum[3])) * (1.f / 4096.f);
}

// ---------------------------------------------------------------------------
extern "C" void kernel_launch(void* const* d_in, const int* in_sizes, int n_in,
                              void* d_out, int out_size, void* d_ws, size_t ws_size,
                              hipStream_t stream)
{
    const int*   labels = (const int*)  d_in[0];
    const float* emb    = (const float*)d_in[1];
    const float* W_in   = (const float*)d_in[2];
    const float* b_in   = (const float*)d_in[3];
    const float* W_sani = (const float*)d_in[4];
    const float* b_sani = (const float*)d_in[5];
    const float* ln_w   = (const float*)d_in[6];
    const float* ln_b   = (const float*)d_in[7];
    const float* W_out  = (const float*)d_in[8];
    const float* b_out  = (const float*)d_in[9];
    float* out = (float*)d_out;

    float* ws = (float*)d_ws;
    float* h0       = ws;                    // 1M floats
    float* hf       = ws + (1 << 20);        // 1M
    float* yb       = ws + 2 * (1 << 20);    // 1M
    float* gbuf     = ws + 3 * (1 << 20);    // 128*16*1024 = 2M
    float* lse      = ws + 5 * (1 << 20);    // 4096
    float* partials = lse + 4096;            // 1024
    int*   prodG    = (int*)(partials + 1024);   // 128*32 ints
    int*   consG    = prodG + NBLK_SCAN * 32;

    gemm_relu_kernel<true><<<dim3(256), dim3(256), 0, stream>>>(
        nullptr, labels, emb, W_in, b_in, h0, prodG, consG);
    // Regular launch: 128 blocks x 512 thr x 66 KB LDS always co-resident on
    // 256 CUs; no cooperative API (graph-capturable, no validation overhead).
    scan_kernel<<<dim3(NBLK_SCAN), dim3(512), 0, stream>>>(
        h0, hf, W_sani, b_sani, ln_w, ln_b, gbuf, prodG, consG);
    gemm_relu_kernel<false><<<dim3(256), dim3(256), 0, stream>>>(
        hf, nullptr, emb, W_out, b_out, yb, nullptr, nullptr);
    lse_kernel<<<dim3(64), dim3(256), 0, stream>>>(yb, lse);
    loss_row_kernel<<<dim3(1024), dim3(256), 0, stream>>>(
        yb, labels, emb, lse, partials);
    loss_final_kernel<<<dim3(1), dim3(256), 0, stream>>>(partials, out);
}